// Round 1
// 266.136 us; speedup vs baseline: 1.0683x; 1.0683x over previous
//
#include <hip/hip_runtime.h>
#include <hip/hip_bf16.h>
#include <stdint.h>

#define B_ 8
#define T_ 2048
#define C_ 384
#define H_ 6
#define D_ 64
#define M_ (B_*T_)   // 16384

typedef unsigned short u16;
typedef unsigned int u32;
typedef __attribute__((ext_vector_type(8))) short short8;
typedef __attribute__((ext_vector_type(4))) float floatx4;
typedef __attribute__((ext_vector_type(16))) float floatx16;

__device__ __forceinline__ float b2f(u16 v) {
  union { unsigned u; float f; } x; x.u = ((unsigned)v) << 16; return x.f;
}
__device__ __forceinline__ u16 f2b(float f) {
  union { float f; unsigned u; } x; x.f = f;
  unsigned r = x.u + 0x7fffu + ((x.u >> 16) & 1u);  // round-nearest-even
  return (u16)(r >> 16);
}
__device__ __forceinline__ u32 pack_bf16(float a, float b) {
  union { __hip_bfloat162 h; u32 u; } x;
  x.h = __float22bfloat162_rn(float2{a, b});
  return x.u;
}
__device__ __forceinline__ uint4 pack8(const float4& lo, const float4& hi) {
  uint4 r;
  r.x = pack_bf16(lo.x, lo.y); r.y = pack_bf16(lo.z, lo.w);
  r.z = pack_bf16(hi.x, hi.y); r.w = pack_bf16(hi.z, hi.w);
  return r;
}

// v_permlane32_swap: a.hi <- b.lo ; b.lo <- a.hi  (lo halves of a, hi of b keep)
__device__ __forceinline__ void plswap(u32& a, u32& b) {
#if __has_builtin(__builtin_amdgcn_permlane32_swap)
  auto r = __builtin_amdgcn_permlane32_swap(a, b, false, false);
  a = r[0]; b = r[1];
#else
  u32 xa = (u32)__shfl_xor((int)a, 32, 64);
  u32 xb = (u32)__shfl_xor((int)b, 32, 64);
  int h = (int)((threadIdx.x & 63) >> 5);
  u32 na = h ? xb : a;
  u32 nb = h ? b : xa;
  a = na; b = nb;
#endif
}

// ---------------------------------------------------------------------------
// Fused QKV projection (unchanged from round-9 config).
// ---------------------------------------------------------------------------
__global__ __launch_bounds__(256) void qkv_fused(
    const float* __restrict__ Xf,
    const float* __restrict__ Wqf, const float* __restrict__ Wkf, const float* __restrict__ Wvf,
    const float* __restrict__ cosb, const float* __restrict__ sinb,
    u16* __restrict__ Qo, u16* __restrict__ Ko, u16* __restrict__ Vto)
{
  __shared__ __align__(16) u16 smem[128 * 64 + 3 * 64 * 64];  // As | Bs[3] (40 KB)
  u16* As = smem;
  u16* Bs0 = smem + 128 * 64;

  const int m0 = blockIdx.x * 128;
  const int hh = blockIdx.y;
  const int n0 = hh * 64;

  const int tid = threadIdx.x;
  const int w = tid >> 6;
  const int lane = tid & 63;
  const int quad = lane >> 4;
  const int c = lane & 15;

  const float* Wz[3] = {Wqf, Wkf, Wvf};

  floatx4 acc[3][2][4];
#pragma unroll
  for (int z = 0; z < 3; z++)
#pragma unroll
    for (int i = 0; i < 2; i++)
#pragma unroll
      for (int j = 0; j < 4; j++) acc[z][i][j] = (floatx4){0.f, 0.f, 0.f, 0.f};

  const int ra = tid >> 1, ca = (tid & 1) * 4;   // A: 2 thr/row, 4 chunks each
  const int rb = tid >> 2, cb = (tid & 3) * 2;   // B: 4 thr/row, 2 chunks each

  for (int k0 = 0; k0 < 384; k0 += 64) {
    float4 af[8];
#pragma unroll
    for (int j = 0; j < 4; j++) {
      const float* p = Xf + (size_t)(m0 + ra) * C_ + k0 + (ca + j) * 8;
      af[2 * j]     = *reinterpret_cast<const float4*>(p);
      af[2 * j + 1] = *reinterpret_cast<const float4*>(p + 4);
    }
    float4 bw[3][4];
#pragma unroll
    for (int z = 0; z < 3; z++)
#pragma unroll
      for (int u = 0; u < 2; u++) {
        const float* p = Wz[z] + (size_t)(n0 + rb) * C_ + k0 + (cb + u) * 8;
        bw[z][2 * u]     = *reinterpret_cast<const float4*>(p);
        bw[z][2 * u + 1] = *reinterpret_cast<const float4*>(p + 4);
      }
    __syncthreads();
#pragma unroll
    for (int j = 0; j < 4; j++)
      *reinterpret_cast<uint4*>(As + ra * 64 + (((ca + j) ^ (ra & 7)) * 8)) =
          pack8(af[2 * j], af[2 * j + 1]);
#pragma unroll
    for (int z = 0; z < 3; z++)
#pragma unroll
      for (int u = 0; u < 2; u++)
        *reinterpret_cast<uint4*>(Bs0 + z * 4096 + rb * 64 + (((cb + u) ^ (rb & 7)) * 8)) =
            pack8(bw[z][2 * u], bw[z][2 * u + 1]);
    __syncthreads();

#pragma unroll
    for (int ks = 0; ks < 2; ks++) {
      short8 af2[2];
#pragma unroll
      for (int mi = 0; mi < 2; mi++) {
        int row = w * 32 + mi * 16 + c;
        af2[mi] = *reinterpret_cast<const short8*>(
            As + row * 64 + (((ks * 4 + quad) ^ (row & 7)) * 8));
      }
#pragma unroll
      for (int z = 0; z < 3; z++) {
#pragma unroll
        for (int ni = 0; ni < 4; ni++) {
          int row = ni * 16 + c;
          short8 bf = *reinterpret_cast<const short8*>(
              Bs0 + z * 4096 + row * 64 + (((ks * 4 + quad) ^ (row & 7)) * 8));
#pragma unroll
          for (int mi = 0; mi < 2; mi++)
            acc[z][mi][ni] = __builtin_amdgcn_mfma_f32_16x16x32_bf16(af2[mi], bf, acc[z][mi][ni], 0, 0, 0);
        }
      }
    }
  }

  const int bb2 = m0 >> 11;
  const int tbase = m0 & (T_ - 1);

  // ---- V: register scatter to Vt[B][H][D][T] ----
  {
    const size_t vbase = ((size_t)(bb2 * H_ + hh)) * D_ * T_;
#pragma unroll
    for (int mi = 0; mi < 2; mi++) {
      int t = tbase + w * 32 + mi * 16 + quad * 4;
#pragma unroll
      for (int ni = 0; ni < 4; ni++) {
        int d = ni * 16 + c;
        ushort4 pk;
        pk.x = f2b(acc[2][mi][ni][0]); pk.y = f2b(acc[2][mi][ni][1]);
        pk.z = f2b(acc[2][mi][ni][2]); pk.w = f2b(acc[2][mi][ni][3]);
        *reinterpret_cast<ushort4*>(Vto + vbase + (size_t)d * T_ + t) = pk;
      }
    }
  }

  // ---- Q then K: lane-parallel RMS + RoPE, LDS transpose store ----
  u16* Ep = smem;
#pragma unroll
  for (int zz = 0; zz < 2; zz++) {
    __syncthreads();
#pragma unroll
    for (int mi = 0; mi < 2; mi++) {
      float ssr[4];
#pragma unroll
      for (int r = 0; r < 4; r++) {
        float s0 = acc[zz][mi][0][r], s1 = acc[zz][mi][1][r];
        float s2 = acc[zz][mi][2][r], s3 = acc[zz][mi][3][r];
        ssr[r] = s0 * s0 + s1 * s1 + s2 * s2 + s3 * s3;
      }
#pragma unroll
      for (int off = 1; off < 16; off <<= 1)
#pragma unroll
        for (int r = 0; r < 4; r++) ssr[r] += __shfl_xor(ssr[r], off, 64);
      int rowb = w * 32 + mi * 16 + quad * 4;
#pragma unroll
      for (int r = 0; r < 4; r++) {
        float scale = rsqrtf(ssr[r] * (1.0f / 64.0f) + 1e-5f);
        int t = tbase + rowb + r;
#pragma unroll
        for (int h2 = 0; h2 < 2; h2++) {
          float cs = cosb[t * 32 + h2 * 16 + c];
          float sn = sinb[t * 32 + h2 * 16 + c];
          float x1 = acc[zz][mi][h2][r];
          float x2 = acc[zz][mi][h2 + 2][r];
          Ep[(rowb + r) * 72 + h2 * 16 + c]       = f2b((x1 * cs + x2 * sn) * scale);
          Ep[(rowb + r) * 72 + (h2 + 2) * 16 + c] = f2b((x2 * cs - x1 * sn) * scale);
        }
      }
    }
    __syncthreads();
    {
      int row = tid >> 1, half = tid & 1;
      int t = tbase + row;
      u16* Og = (zz == 0) ? Qo : Ko;
      u16* dst = Og + (((size_t)(bb2 * H_ + hh)) * T_ + t) * D_ + half * 32;
#pragma unroll
      for (int i = 0; i < 4; i++)
        *reinterpret_cast<uint4*>(dst + i * 8) =
            *reinterpret_cast<const uint4*>(Ep + row * 72 + half * 32 + i * 8);
    }
  }
}

// ---------------------------------------------------------------------------
// MFMA flash attention — 32x32x16 swapped-QK^T restructure (T12 in-register
// softmax).  4 waves x 32 q-rows = 128 q/block, KVBLK=64.  Each lane holds a
// full 32-wide P-row slice for q = lane&31 -> softmax fully in-lane; P->bf16
// via cvt_pk + v_permlane32_swap (no ds_bpermute repack).  T14 staging split:
// issue next-tile global loads before compute, LDS-write after drain barrier.
// Fixed-max softmax: s in [-8,8] after RMS-norm, p = exp2(s*0.125*log2e - 8*log2e).
// ---------------------------------------------------------------------------
#define EXP2_SC 0.1803368801111244f    // 0.125 * log2(e)
#define EXP2_BI (-11.541560327111404f) // -8 * log2(e)

__global__ __launch_bounds__(256) void attn_mfma(
    const u16* __restrict__ Qg, const u16* __restrict__ Kg,
    const u16* __restrict__ Vtg, u16* __restrict__ Yg)
{
  // Ks[64][64] | Vs[64][64] bf16 (16 KB); epilogue reuses as 4 x 32 x 72 u16 (18 KB)
  __shared__ __align__(16) u16 smem[9216];
  u16* Ks = smem;
  u16* Vs = smem + 4096;

  const int tid = threadIdx.x;
  const int w = tid >> 6;
  const int lane = tid & 63;
  const int hi = lane >> 5;     // which half of the wave (k-slot group)
  const int lq = lane & 31;     // q column (QK^T) / d column (PV) / t row (K frag)

  const int bh = blockIdx.y;
  const int q0 = blockIdx.x * 128;
  const size_t baseQK = (size_t)bh * T_ * D_;
  const size_t baseV  = (size_t)bh * D_ * T_;

  // Q fragments (B-operand): lane holds Q[q0+w*32+lq][ds*16 + hi*8 + j]
  short8 qf[4];
  {
    const u16* qp = Qg + baseQK + (size_t)(q0 + w * 32 + lq) * D_ + hi * 8;
#pragma unroll
    for (int d = 0; d < 4; d++)
      qf[d] = *reinterpret_cast<const short8*>(qp + d * 16);
  }

  // staging addresses: 256 threads cover 64 rows x 2 x 16B chunks each
  const int sr = tid >> 2;      // 0..63 (t-row for K, d-row for V^T)
  const int sch = tid & 3;      // chunk 0..3 (and +4)
  const u16* kga = Kg + baseQK + (size_t)sr * D_ + sch * 8;
  const u16* vga = Vtg + baseV + (size_t)sr * T_ + sch * 8;
  u16* ksw0 = Ks + sr * 64 + (((sch) ^ (sr & 7)) * 8);
  u16* ksw1 = Ks + sr * 64 + (((sch + 4) ^ (sr & 7)) * 8);
  u16* vsw0 = Vs + sr * 64 + (((sch) ^ (sr & 7)) * 8);
  u16* vsw1 = Vs + sr * 64 + (((sch + 4) ^ (sr & 7)) * 8);

  // prologue: load tile 0 into regs
  uint4 ka = *reinterpret_cast<const uint4*>(kga);
  uint4 kb = *reinterpret_cast<const uint4*>(kga + 32);
  uint4 va = *reinterpret_cast<const uint4*>(vga);
  uint4 vb = *reinterpret_cast<const uint4*>(vga + 32);

  floatx16 o0, o1;
#pragma unroll
  for (int i = 0; i < 16; i++) { o0[i] = 0.f; o1[i] = 0.f; }
  float l_part = 0.f;

  for (int kt = 0; kt < T_; kt += 64) {
    // write staged regs -> LDS (implicit vmcnt wait lands here, after compute
    // of the previous tile already covered the load latency)
    *reinterpret_cast<uint4*>(ksw0) = ka;
    *reinterpret_cast<uint4*>(ksw1) = kb;
    *reinterpret_cast<uint4*>(vsw0) = va;
    *reinterpret_cast<uint4*>(vsw1) = vb;
    __syncthreads();

    // issue next-tile loads early (overlap with this tile's compute)
    if (kt + 64 < T_) {
      const u16* kp = kga + (size_t)(kt + 64) * D_;
      const u16* vp = vga + (kt + 64);
      ka = *reinterpret_cast<const uint4*>(kp);
      kb = *reinterpret_cast<const uint4*>(kp + 32);
      va = *reinterpret_cast<const uint4*>(vp);
      vb = *reinterpret_cast<const uint4*>(vp + 32);
    }

    // ---- QK^T (swapped): st = K * Q^T, col = q (lane-local), rows = t ----
    floatx16 st0, st1;
#pragma unroll
    for (int i = 0; i < 16; i++) { st0[i] = 0.f; st1[i] = 0.f; }
#pragma unroll
    for (int ds = 0; ds < 4; ds++) {
      const int xr = (ds * 2 + hi) ^ (lq & 7);   // (32+lq)&7 == lq&7
      short8 kf0 = *reinterpret_cast<const short8*>(Ks + lq * 64 + xr * 8);
      short8 kf1 = *reinterpret_cast<const short8*>(Ks + (32 + lq) * 64 + xr * 8);
      st0 = __builtin_amdgcn_mfma_f32_32x32x16_bf16(kf0, qf[ds], st0, 0, 0, 0);
      st1 = __builtin_amdgcn_mfma_f32_32x32x16_bf16(kf1, qf[ds], st1, 0, 0, 0);
    }

    // ---- in-lane fixed-max softmax: p = exp2(s*SC + BI), all 32 t local ----
#pragma unroll
    for (int r = 0; r < 16; r++) {
      float p0 = exp2f(fmaf(st0[r], EXP2_SC, EXP2_BI));
      float p1 = exp2f(fmaf(st1[r], EXP2_SC, EXP2_BI));
      st0[r] = p0; st1[r] = p1;
      l_part += p0 + p1;
    }

    // ---- P -> bf16 A-fragments: 16 cvt_pk + 8 permlane32_swap (T12) ----
    // lane holds t = tt*32 + (r&3) + 8*(r>>2) + 4*hi; A-frag ks needs
    // t = ks*16 + hi*8 + j  ->  one half-swap per reg pair.
    short8 pa[4];
#pragma unroll
    for (int ks = 0; ks < 4; ks++) {
      const floatx16& s = (ks < 2) ? st0 : st1;
      const int rb = (ks & 1) * 8;
      u32 ca = pack_bf16(s[rb + 0], s[rb + 1]);
      u32 cb = pack_bf16(s[rb + 2], s[rb + 3]);
      u32 cc = pack_bf16(s[rb + 4], s[rb + 5]);
      u32 cd = pack_bf16(s[rb + 6], s[rb + 7]);
      plswap(ca, cc);
      plswap(cb, cd);
      short8 pf;
      u32* pfu = reinterpret_cast<u32*>(&pf);
      pfu[0] = ca; pfu[1] = cb; pfu[2] = cc; pfu[3] = cd;
      pa[ks] = pf;
    }

    // ---- PV: O[q][d] += P * V, A = P (in-reg), B = V^T from LDS ----
#pragma unroll
    for (int nt = 0; nt < 2; nt++) {
      const int d = nt * 32 + lq;
      floatx16& o = nt ? o1 : o0;
#pragma unroll
      for (int ks = 0; ks < 4; ks++) {
        short8 vf = *reinterpret_cast<const short8*>(
            Vs + d * 64 + ((((ks * 2 + hi)) ^ (d & 7)) * 8));
        o = __builtin_amdgcn_mfma_f32_32x32x16_bf16(pa[ks], vf, o, 0, 0, 0);
      }
    }
    __syncthreads();   // all waves done reading LDS before next tile's writes
  }

  // l for q = lq: both wave halves hold partial sums over disjoint t
  float l_full = l_part + __shfl_xor(l_part, 32, 64);
  float inv = 1.0f / l_full;

  // redistribute inv to the row-mapped q each accumulator register holds
  float invr[16];
#pragma unroll
  for (int r = 0; r < 16; r++) {
    const int qr = (r & 3) + 8 * (r >> 2) + 4 * hi;
    invr[r] = __shfl(inv, qr, 64);
  }

  // epilogue: LDS transpose (row = q-local, col = d) then coalesced stores
  u16* Ep = smem + w * (32 * 72);
#pragma unroll
  for (int nt = 0; nt < 2; nt++) {
    const floatx16& o = nt ? o1 : o0;
#pragma unroll
    for (int r = 0; r < 16; r++) {
      const int rl = (r & 3) + 8 * (r >> 2) + 4 * hi;
      Ep[rl * 72 + nt * 32 + lq] = f2b(o[r] * invr[r]);
    }
  }
  __syncthreads();
  {
    const int row = tid >> 1, half = tid & 1;   // 128 rows x 2 halves of 64B
    const u16* src = smem + (row >> 5) * (32 * 72) + (row & 31) * 72 + half * 32;
    const int t = q0 + row;
    const int b = bh / H_, h = bh % H_;
    const size_t yi = ((size_t)b * T_ + t) * C_ + (size_t)h * 64 + half * 32;
#pragma unroll
    for (int i = 0; i < 4; i++)
      *reinterpret_cast<uint4*>(Yg + yi + i * 8) =
          *reinterpret_cast<const uint4*>(src + i * 8);
  }
}

// ---------------------------------------------------------------------------
// Out projection (unchanged from round-9 config).
// ---------------------------------------------------------------------------
__global__ __launch_bounds__(256) void out_mfma(
    const u16* __restrict__ Xb, const float* __restrict__ Wf, float* __restrict__ Og)
{
  __shared__ __align__(16) u16 smem[17408];   // As|Bs, then fp32 Ep (34816 B)
  u16* As = smem;
  u16* Bs = smem + 128 * 64;

  const int m0 = blockIdx.x * 128;
  const int n0 = blockIdx.y * 64;

  const int tid = threadIdx.x;
  const int w = tid >> 6;
  const int lane = tid & 63;
  const int quad = lane >> 4;
  const int c = lane & 15;

  floatx4 acc[2][4];
#pragma unroll
  for (int i = 0; i < 2; i++)
#pragma unroll
    for (int j = 0; j < 4; j++) acc[i][j] = (floatx4){0.f, 0.f, 0.f, 0.f};

  const int ra = tid >> 1, ca = (tid & 1) * 4;
  const int rb = tid >> 2, cb = (tid & 3) * 2;

  for (int k0 = 0; k0 < 384; k0 += 64) {
    uint4 a[4];
#pragma unroll
    for (int j = 0; j < 4; j++)
      a[j] = *reinterpret_cast<const uint4*>(Xb + (size_t)(m0 + ra) * C_ + k0 + (ca + j) * 8);
    float4 bw[4];
#pragma unroll
    for (int u = 0; u < 2; u++) {
      const float* p = Wf + (size_t)(n0 + rb) * C_ + k0 + (cb + u) * 8;
      bw[2 * u]     = *reinterpret_cast<const float4*>(p);
      bw[2 * u + 1] = *reinterpret_cast<const float4*>(p + 4);
    }
    __syncthreads();
#pragma unroll
    for (int j = 0; j < 4; j++)
      *reinterpret_cast<uint4*>(As + ra * 64 + (((ca + j) ^ (ra & 7)) * 8)) = a[j];
#pragma unroll
    for (int u = 0; u < 2; u++)
      *reinterpret_cast<uint4*>(Bs + rb * 64 + (((cb + u) ^ (rb & 7)) * 8)) =
          pack8(bw[2 * u], bw[2 * u + 1]);
    __syncthreads();

#pragma unroll
    for (int ks = 0; ks < 2; ks++) {
      short8 af[2], bf[4];
#pragma unroll
      for (int mi = 0; mi < 2; mi++) {
        int row = w * 32 + mi * 16 + c;
        af[mi] = *reinterpret_cast<const short8*>(
            As + row * 64 + (((ks * 4 + quad) ^ (row & 7)) * 8));
      }
#pragma unroll
      for (int ni = 0; ni < 4; ni++) {
        int row = ni * 16 + c;
        bf[ni] = *reinterpret_cast<const short8*>(
            Bs + row * 64 + (((ks * 4 + quad) ^ (row & 7)) * 8));
      }
#pragma unroll
      for (int mi = 0; mi < 2; mi++)
#pragma unroll
        for (int ni = 0; ni < 4; ni++)
          acc[mi][ni] = __builtin_amdgcn_mfma_f32_16x16x32_bf16(af[mi], bf[ni], acc[mi][ni], 0, 0, 0);
    }
  }

  __syncthreads();
  float* Ep = reinterpret_cast<float*>(smem) + w * (32 * 68);
#pragma unroll
  for (int mi = 0; mi < 2; mi++)
#pragma unroll
    for (int ni = 0; ni < 4; ni++) {
      int rw = mi * 16 + quad * 4;
      int col = ni * 16 + c;
#pragma unroll
      for (int r = 0; r < 4; r++)
        Ep[(rw + r) * 68 + col] = acc[mi][ni][r];
    }
  __syncthreads();
  {
    int rw2 = lane >> 1, half = lane & 1;
    const float* src = Ep + rw2 * 68 + half * 32;
    float* dst = Og + (size_t)(m0 + w * 32 + rw2) * C_ + n0 + half * 32;
#pragma unroll
    for (int i = 0; i < 8; i++)
      *reinterpret_cast<float4*>(dst + i * 4) =
          *reinterpret_cast<const float4*>(src + i * 4);
  }
}

// ---------------------------------------------------------------------------
extern "C" void kernel_launch(void* const* d_in, const int* in_sizes, int n_in,
                              void* d_out, int out_size, void* d_ws, size_t ws_size,
                              hipStream_t stream) {
  (void)in_sizes; (void)n_in; (void)out_size; (void)ws_size;
  const float* x    = (const float*)d_in[0];
  const float* Wq   = (const float*)d_in[1];
  const float* Wk   = (const float*)d_in[2];
  const float* Wv   = (const float*)d_in[3];
  const float* Wo   = (const float*)d_in[4];
  const float* cosb = (const float*)d_in[5];
  const float* sinb = (const float*)d_in[6];

  const size_t MC = (size_t)M_ * C_;    // 6291456
  u16* ws = (u16*)d_ws;
  u16* Q   = ws;                        // [B][H][T][D] bf16
  u16* K   = Q + MC;
  u16* Vt  = K + MC;                    // [B][H][D][T] bf16
  u16* Y   = Vt + MC;                   // [B*T][C] bf16
  float* out = (float*)d_out;

  qkv_fused<<<dim3(M_ / 128, H_), 256, 0, stream>>>(
      x, Wq, Wk, Wv, cosb, sinb, Q, K, Vt);

  attn_mfma<<<dim3(T_ / 128, B_ * H_), 256, 0, stream>>>(Q, K, Vt, Y);

  out_mfma<<<dim3(M_ / 128, H_), 256, 0, stream>>>(Y, Wo, out);
}

// Round 2
// 255.127 us; speedup vs baseline: 1.1144x; 1.0431x over previous
//
#include <hip/hip_runtime.h>
#include <hip/hip_bf16.h>
#include <stdint.h>

#define B_ 8
#define T_ 2048
#define C_ 384
#define H_ 6
#define D_ 64
#define M_ (B_*T_)   // 16384

typedef unsigned short u16;
typedef unsigned int u32;
typedef __attribute__((ext_vector_type(8))) short short8;
typedef __attribute__((ext_vector_type(4))) float floatx4;
typedef __attribute__((ext_vector_type(16))) float floatx16;

// softmax scale folded into stored Q: 0.125 * log2(e)
#define QSCALE 0.18033688011112042f

__device__ __forceinline__ u16 f2b(float f) {
  union { float f; unsigned u; } x; x.f = f;
  unsigned r = x.u + 0x7fffu + ((x.u >> 16) & 1u);  // round-nearest-even
  return (u16)(r >> 16);
}
__device__ __forceinline__ u32 pack_bf16(float a, float b) {
  union { __hip_bfloat162 h; u32 u; } x;
  x.h = __float22bfloat162_rn(float2{a, b});
  return x.u;
}
__device__ __forceinline__ uint4 pack8(const float4& lo, const float4& hi) {
  uint4 r;
  r.x = pack_bf16(lo.x, lo.y); r.y = pack_bf16(lo.z, lo.w);
  r.z = pack_bf16(hi.x, hi.y); r.w = pack_bf16(hi.z, hi.w);
  return r;
}

// v_permlane32_swap_b32: swaps a.hi(32 lanes) <-> b.lo(32 lanes).  Guaranteed
// VALU (no ds_bpermute) — semantics identical to the previously-passing path.
__device__ __forceinline__ void plswap(u32& a, u32& b) {
  asm("v_permlane32_swap_b32 %0, %1" : "+v"(a), "+v"(b));
}

// ---------------------------------------------------------------------------
// Fused QKV projection.  Q output is pre-scaled by 0.125*log2(e) so the
// attention softmax is a bare exp2 (bias constant cancels in p/l).
// ---------------------------------------------------------------------------
__global__ __launch_bounds__(256) void qkv_fused(
    const float* __restrict__ Xf,
    const float* __restrict__ Wqf, const float* __restrict__ Wkf, const float* __restrict__ Wvf,
    const float* __restrict__ cosb, const float* __restrict__ sinb,
    u16* __restrict__ Qo, u16* __restrict__ Ko, u16* __restrict__ Vto)
{
  __shared__ __align__(16) u16 smem[128 * 64 + 3 * 64 * 64];  // As | Bs[3] (40 KB)
  u16* As = smem;
  u16* Bs0 = smem + 128 * 64;

  const int m0 = blockIdx.x * 128;
  const int hh = blockIdx.y;
  const int n0 = hh * 64;

  const int tid = threadIdx.x;
  const int w = tid >> 6;
  const int lane = tid & 63;
  const int quad = lane >> 4;
  const int c = lane & 15;

  const float* Wz[3] = {Wqf, Wkf, Wvf};

  floatx4 acc[3][2][4];
#pragma unroll
  for (int z = 0; z < 3; z++)
#pragma unroll
    for (int i = 0; i < 2; i++)
#pragma unroll
      for (int j = 0; j < 4; j++) acc[z][i][j] = (floatx4){0.f, 0.f, 0.f, 0.f};

  const int ra = tid >> 1, ca = (tid & 1) * 4;   // A: 2 thr/row, 4 chunks each
  const int rb = tid >> 2, cb = (tid & 3) * 2;   // B: 4 thr/row, 2 chunks each

  for (int k0 = 0; k0 < 384; k0 += 64) {
    float4 af[8];
#pragma unroll
    for (int j = 0; j < 4; j++) {
      const float* p = Xf + (size_t)(m0 + ra) * C_ + k0 + (ca + j) * 8;
      af[2 * j]     = *reinterpret_cast<const float4*>(p);
      af[2 * j + 1] = *reinterpret_cast<const float4*>(p + 4);
    }
    float4 bw[3][4];
#pragma unroll
    for (int z = 0; z < 3; z++)
#pragma unroll
      for (int u = 0; u < 2; u++) {
        const float* p = Wz[z] + (size_t)(n0 + rb) * C_ + k0 + (cb + u) * 8;
        bw[z][2 * u]     = *reinterpret_cast<const float4*>(p);
        bw[z][2 * u + 1] = *reinterpret_cast<const float4*>(p + 4);
      }
    __syncthreads();
#pragma unroll
    for (int j = 0; j < 4; j++)
      *reinterpret_cast<uint4*>(As + ra * 64 + (((ca + j) ^ (ra & 7)) * 8)) =
          pack8(af[2 * j], af[2 * j + 1]);
#pragma unroll
    for (int z = 0; z < 3; z++)
#pragma unroll
      for (int u = 0; u < 2; u++)
        *reinterpret_cast<uint4*>(Bs0 + z * 4096 + rb * 64 + (((cb + u) ^ (rb & 7)) * 8)) =
            pack8(bw[z][2 * u], bw[z][2 * u + 1]);
    __syncthreads();

#pragma unroll
    for (int ks = 0; ks < 2; ks++) {
      short8 af2[2];
#pragma unroll
      for (int mi = 0; mi < 2; mi++) {
        int row = w * 32 + mi * 16 + c;
        af2[mi] = *reinterpret_cast<const short8*>(
            As + row * 64 + (((ks * 4 + quad) ^ (row & 7)) * 8));
      }
#pragma unroll
      for (int z = 0; z < 3; z++) {
#pragma unroll
        for (int ni = 0; ni < 4; ni++) {
          int row = ni * 16 + c;
          short8 bf = *reinterpret_cast<const short8*>(
              Bs0 + z * 4096 + row * 64 + (((ks * 4 + quad) ^ (row & 7)) * 8));
#pragma unroll
          for (int mi = 0; mi < 2; mi++)
            acc[z][mi][ni] = __builtin_amdgcn_mfma_f32_16x16x32_bf16(af2[mi], bf, acc[z][mi][ni], 0, 0, 0);
        }
      }
    }
  }

  const int bb2 = m0 >> 11;
  const int tbase = m0 & (T_ - 1);

  // ---- V: register scatter to Vt[B][H][D][T] ----
  {
    const size_t vbase = ((size_t)(bb2 * H_ + hh)) * D_ * T_;
#pragma unroll
    for (int mi = 0; mi < 2; mi++) {
      int t = tbase + w * 32 + mi * 16 + quad * 4;
#pragma unroll
      for (int ni = 0; ni < 4; ni++) {
        int d = ni * 16 + c;
        ushort4 pk;
        pk.x = f2b(acc[2][mi][ni][0]); pk.y = f2b(acc[2][mi][ni][1]);
        pk.z = f2b(acc[2][mi][ni][2]); pk.w = f2b(acc[2][mi][ni][3]);
        *reinterpret_cast<ushort4*>(Vto + vbase + (size_t)d * T_ + t) = pk;
      }
    }
  }

  // ---- Q then K: lane-parallel RMS + RoPE, LDS transpose store ----
  u16* Ep = smem;
#pragma unroll
  for (int zz = 0; zz < 2; zz++) {
    __syncthreads();
#pragma unroll
    for (int mi = 0; mi < 2; mi++) {
      float ssr[4];
#pragma unroll
      for (int r = 0; r < 4; r++) {
        float s0 = acc[zz][mi][0][r], s1 = acc[zz][mi][1][r];
        float s2 = acc[zz][mi][2][r], s3 = acc[zz][mi][3][r];
        ssr[r] = s0 * s0 + s1 * s1 + s2 * s2 + s3 * s3;
      }
#pragma unroll
      for (int off = 1; off < 16; off <<= 1)
#pragma unroll
        for (int r = 0; r < 4; r++) ssr[r] += __shfl_xor(ssr[r], off, 64);
      int rowb = w * 32 + mi * 16 + quad * 4;
#pragma unroll
      for (int r = 0; r < 4; r++) {
        float scl = rsqrtf(ssr[r] * (1.0f / 64.0f) + 1e-5f);
        if (zz == 0) scl *= QSCALE;     // fold softmax scale into Q
        int t = tbase + rowb + r;
#pragma unroll
        for (int h2 = 0; h2 < 2; h2++) {
          float cs = cosb[t * 32 + h2 * 16 + c];
          float sn = sinb[t * 32 + h2 * 16 + c];
          float x1 = acc[zz][mi][h2][r];
          float x2 = acc[zz][mi][h2 + 2][r];
          Ep[(rowb + r) * 72 + h2 * 16 + c]       = f2b((x1 * cs + x2 * sn) * scl);
          Ep[(rowb + r) * 72 + (h2 + 2) * 16 + c] = f2b((x2 * cs - x1 * sn) * scl);
        }
      }
    }
    __syncthreads();
    {
      int row = tid >> 1, half = tid & 1;
      int t = tbase + row;
      u16* Og = (zz == 0) ? Qo : Ko;
      u16* dst = Og + (((size_t)(bb2 * H_ + hh)) * T_ + t) * D_ + half * 32;
#pragma unroll
      for (int i = 0; i < 4; i++)
        *reinterpret_cast<uint4*>(dst + i * 8) =
            *reinterpret_cast<const uint4*>(Ep + row * 72 + half * 32 + i * 8);
    }
  }
}

// ---------------------------------------------------------------------------
// MFMA flash attention — 32x32x16 swapped-QK^T, in-register softmax.
// Round-2 VALU diet: asm permlane32_swap, bare exp2 (scale folded into Q,
// bias dropped — cancels in p/l), hoisted zero C-operand, l via ones-MFMA
// (row mapping matches o exactly -> zero shuffles for normalization).
// ---------------------------------------------------------------------------
__global__ __launch_bounds__(256, 3) void attn_mfma(
    const u16* __restrict__ Qg, const u16* __restrict__ Kg,
    const u16* __restrict__ Vtg, u16* __restrict__ Yg)
{
  // Ks[64][64] | Vs[64][64] bf16 (16 KB); epilogue reuses as 4 x 32 x 72 u16 (18 KB)
  __shared__ __align__(16) u16 smem[9216];
  u16* Ks = smem;
  u16* Vs = smem + 4096;

  const int tid = threadIdx.x;
  const int w = tid >> 6;
  const int lane = tid & 63;
  const int hi = lane >> 5;     // which half of the wave (k-slot group)
  const int lq = lane & 31;     // q column (QK^T) / d column (PV) / t row (K frag)

  const int bh = blockIdx.y;
  const int q0 = blockIdx.x * 128;
  const size_t baseQK = (size_t)bh * T_ * D_;
  const size_t baseV  = (size_t)bh * D_ * T_;

  // Q fragments (B-operand): lane holds Q[q0+w*32+lq][ds*16 + hi*8 + j]
  short8 qf[4];
  {
    const u16* qp = Qg + baseQK + (size_t)(q0 + w * 32 + lq) * D_ + hi * 8;
#pragma unroll
    for (int d = 0; d < 4; d++)
      qf[d] = *reinterpret_cast<const short8*>(qp + d * 16);
  }

  // loop-invariant zero C-operand (materialized once, not per tile)
  floatx16 z16;
#pragma unroll
  for (int i = 0; i < 16; i++) z16[i] = 0.f;
  // loop-invariant ones B-fragment (bf16 1.0) for the l-row-sum MFMA
  short8 vones;
#pragma unroll
  for (int i = 0; i < 8; i++) vones[i] = (short)0x3F80;

  // staging addresses: 256 threads cover 64 rows x 2 x 16B chunks each
  const int sr = tid >> 2;      // 0..63 (t-row for K, d-row for V^T)
  const int sch = tid & 3;      // chunk 0..3 (and +4)
  const u16* kga = Kg + baseQK + (size_t)sr * D_ + sch * 8;
  const u16* vga = Vtg + baseV + (size_t)sr * T_ + sch * 8;
  u16* ksw0 = Ks + sr * 64 + (((sch) ^ (sr & 7)) * 8);
  u16* ksw1 = Ks + sr * 64 + (((sch + 4) ^ (sr & 7)) * 8);
  u16* vsw0 = Vs + sr * 64 + (((sch) ^ (sr & 7)) * 8);
  u16* vsw1 = Vs + sr * 64 + (((sch + 4) ^ (sr & 7)) * 8);

  // prologue: load tile 0 into regs; running next-tile pointers
  uint4 ka = *reinterpret_cast<const uint4*>(kga);
  uint4 kb = *reinterpret_cast<const uint4*>(kga + 32);
  uint4 va = *reinterpret_cast<const uint4*>(vga);
  uint4 vb = *reinterpret_cast<const uint4*>(vga + 32);
  const u16* kload = kga + (size_t)64 * D_;
  const u16* vload = vga + 64;

  floatx16 o0 = z16, o1 = z16;
  floatx16 l_acc = z16;

  for (int kt = 0; kt < T_; kt += 64) {
    // write staged regs -> LDS
    *reinterpret_cast<uint4*>(ksw0) = ka;
    *reinterpret_cast<uint4*>(ksw1) = kb;
    *reinterpret_cast<uint4*>(vsw0) = va;
    *reinterpret_cast<uint4*>(vsw1) = vb;
    __syncthreads();

    // issue next-tile loads early (overlap with this tile's compute)
    if (kt + 64 < T_) {
      ka = *reinterpret_cast<const uint4*>(kload);
      kb = *reinterpret_cast<const uint4*>(kload + 32);
      va = *reinterpret_cast<const uint4*>(vload);
      vb = *reinterpret_cast<const uint4*>(vload + 32);
      kload += (size_t)64 * D_;
      vload += 64;
    }

    // ---- QK^T (swapped): st = K * Q^T, col = q (lane-local), rows = t ----
    floatx16 st0, st1;
    {
      const int xr = hi ^ (lq & 7);           // ds = 0
      short8 kf0 = *reinterpret_cast<const short8*>(Ks + lq * 64 + xr * 8);
      short8 kf1 = *reinterpret_cast<const short8*>(Ks + (32 + lq) * 64 + xr * 8);
      st0 = __builtin_amdgcn_mfma_f32_32x32x16_bf16(kf0, qf[0], z16, 0, 0, 0);
      st1 = __builtin_amdgcn_mfma_f32_32x32x16_bf16(kf1, qf[0], z16, 0, 0, 0);
    }
#pragma unroll
    for (int ds = 1; ds < 4; ds++) {
      const int xr = (ds * 2 + hi) ^ (lq & 7);   // (32+lq)&7 == lq&7
      short8 kf0 = *reinterpret_cast<const short8*>(Ks + lq * 64 + xr * 8);
      short8 kf1 = *reinterpret_cast<const short8*>(Ks + (32 + lq) * 64 + xr * 8);
      st0 = __builtin_amdgcn_mfma_f32_32x32x16_bf16(kf0, qf[ds], st0, 0, 0, 0);
      st1 = __builtin_amdgcn_mfma_f32_32x32x16_bf16(kf1, qf[ds], st1, 0, 0, 0);
    }

    // ---- softmax: p = exp2(s)  (scale folded into Q, bias cancels) ----
#pragma unroll
    for (int r = 0; r < 16; r++) {
      st0[r] = exp2f(st0[r]);
      st1[r] = exp2f(st1[r]);
    }

    // ---- P -> bf16 A-fragments: 16 cvt_pk + 8 permlane32_swap ----
    short8 pa[4];
#pragma unroll
    for (int ks = 0; ks < 4; ks++) {
      const floatx16& s = (ks < 2) ? st0 : st1;
      const int rb = (ks & 1) * 8;
      u32 ca = pack_bf16(s[rb + 0], s[rb + 1]);
      u32 cb = pack_bf16(s[rb + 2], s[rb + 3]);
      u32 cc = pack_bf16(s[rb + 4], s[rb + 5]);
      u32 cd = pack_bf16(s[rb + 6], s[rb + 7]);
      plswap(ca, cc);
      plswap(cb, cd);
      short8 pf;
      u32* pfu = reinterpret_cast<u32*>(&pf);
      pfu[0] = ca; pfu[1] = cb; pfu[2] = cc; pfu[3] = cd;
      pa[ks] = pf;
    }

    // ---- PV: O[q][d] += P * V  (A = P in-reg, B = V^T from LDS) ----
#pragma unroll
    for (int nt = 0; nt < 2; nt++) {
      const int d = nt * 32 + lq;
      floatx16& o = nt ? o1 : o0;
#pragma unroll
      for (int ks = 0; ks < 4; ks++) {
        short8 vf = *reinterpret_cast<const short8*>(
            Vs + d * 64 + ((((ks * 2 + hi)) ^ (d & 7)) * 8));
        o = __builtin_amdgcn_mfma_f32_32x32x16_bf16(pa[ks], vf, o, 0, 0, 0);
      }
    }
    // ---- l row-sums via ones-MFMA: same row<->reg mapping as o ----
#pragma unroll
    for (int ks = 0; ks < 4; ks++)
      l_acc = __builtin_amdgcn_mfma_f32_32x32x16_bf16(pa[ks], vones, l_acc, 0, 0, 0);

    __syncthreads();   // all waves done reading LDS before next tile's writes
  }

  // normalization: l_acc[r] holds l for exactly the q-row o[r] holds
  float invr[16];
#pragma unroll
  for (int r = 0; r < 16; r++) invr[r] = 1.0f / l_acc[r];

  // epilogue: LDS transpose (row = q-local, col = d) then coalesced stores
  u16* Ep = smem + w * (32 * 72);
#pragma unroll
  for (int nt = 0; nt < 2; nt++) {
    const floatx16& o = nt ? o1 : o0;
#pragma unroll
    for (int r = 0; r < 16; r++) {
      const int rl = (r & 3) + 8 * (r >> 2) + 4 * hi;
      Ep[rl * 72 + nt * 32 + lq] = f2b(o[r] * invr[r]);
    }
  }
  __syncthreads();
  {
    const int row = tid >> 1, half = tid & 1;   // 128 rows x 2 halves of 64B
    const u16* src = smem + (row >> 5) * (32 * 72) + (row & 31) * 72 + half * 32;
    const int t = q0 + row;
    const int b = bh / H_, h = bh % H_;
    const size_t yi = ((size_t)b * T_ + t) * C_ + (size_t)h * 64 + half * 32;
#pragma unroll
    for (int i = 0; i < 4; i++)
      *reinterpret_cast<uint4*>(Yg + yi + i * 8) =
          *reinterpret_cast<const uint4*>(src + i * 8);
  }
}

// ---------------------------------------------------------------------------
// Out projection (unchanged).
// ---------------------------------------------------------------------------
__global__ __launch_bounds__(256) void out_mfma(
    const u16* __restrict__ Xb, const float* __restrict__ Wf, float* __restrict__ Og)
{
  __shared__ __align__(16) u16 smem[17408];   // As|Bs, then fp32 Ep (34816 B)
  u16* As = smem;
  u16* Bs = smem + 128 * 64;

  const int m0 = blockIdx.x * 128;
  const int n0 = blockIdx.y * 64;

  const int tid = threadIdx.x;
  const int w = tid >> 6;
  const int lane = tid & 63;
  const int quad = lane >> 4;
  const int c = lane & 15;

  floatx4 acc[2][4];
#pragma unroll
  for (int i = 0; i < 2; i++)
#pragma unroll
    for (int j = 0; j < 4; j++) acc[i][j] = (floatx4){0.f, 0.f, 0.f, 0.f};

  const int ra = tid >> 1, ca = (tid & 1) * 4;
  const int rb = tid >> 2, cb = (tid & 3) * 2;

  for (int k0 = 0; k0 < 384; k0 += 64) {
    uint4 a[4];
#pragma unroll
    for (int j = 0; j < 4; j++)
      a[j] = *reinterpret_cast<const uint4*>(Xb + (size_t)(m0 + ra) * C_ + k0 + (ca + j) * 8);
    float4 bw[4];
#pragma unroll
    for (int u = 0; u < 2; u++) {
      const float* p = Wf + (size_t)(n0 + rb) * C_ + k0 + (cb + u) * 8;
      bw[2 * u]     = *reinterpret_cast<const float4*>(p);
      bw[2 * u + 1] = *reinterpret_cast<const float4*>(p + 4);
    }
    __syncthreads();
#pragma unroll
    for (int j = 0; j < 4; j++)
      *reinterpret_cast<uint4*>(As + ra * 64 + (((ca + j) ^ (ra & 7)) * 8)) = a[j];
#pragma unroll
    for (int u = 0; u < 2; u++)
      *reinterpret_cast<uint4*>(Bs + rb * 64 + (((cb + u) ^ (rb & 7)) * 8)) =
          pack8(bw[2 * u], bw[2 * u + 1]);
    __syncthreads();

#pragma unroll
    for (int ks = 0; ks < 2; ks++) {
      short8 af[2], bf[4];
#pragma unroll
      for (int mi = 0; mi < 2; mi++) {
        int row = w * 32 + mi * 16 + c;
        af[mi] = *reinterpret_cast<const short8*>(
            As + row * 64 + (((ks * 4 + quad) ^ (row & 7)) * 8));
      }
#pragma unroll
      for (int ni = 0; ni < 4; ni++) {
        int row = ni * 16 + c;
        bf[ni] = *reinterpret_cast<const short8*>(
            Bs + row * 64 + (((ks * 4 + quad) ^ (row & 7)) * 8));
      }
#pragma unroll
      for (int mi = 0; mi < 2; mi++)
#pragma unroll
        for (int ni = 0; ni < 4; ni++)
          acc[mi][ni] = __builtin_amdgcn_mfma_f32_16x16x32_bf16(af[mi], bf[ni], acc[mi][ni], 0, 0, 0);
    }
  }

  __syncthreads();
  float* Ep = reinterpret_cast<float*>(smem) + w * (32 * 68);
#pragma unroll
  for (int mi = 0; mi < 2; mi++)
#pragma unroll
    for (int ni = 0; ni < 4; ni++) {
      int rw = mi * 16 + quad * 4;
      int col = ni * 16 + c;
#pragma unroll
      for (int r = 0; r < 4; r++)
        Ep[(rw + r) * 68 + col] = acc[mi][ni][r];
    }
  __syncthreads();
  {
    int rw2 = lane >> 1, half = lane & 1;
    const float* src = Ep + rw2 * 68 + half * 32;
    float* dst = Og + (size_t)(m0 + w * 32 + rw2) * C_ + n0 + half * 32;
#pragma unroll
    for (int i = 0; i < 8; i++)
      *reinterpret_cast<float4*>(dst + i * 4) =
          *reinterpret_cast<const float4*>(src + i * 4);
  }
}

// ---------------------------------------------------------------------------
extern "C" void kernel_launch(void* const* d_in, const int* in_sizes, int n_in,
                              void* d_out, int out_size, void* d_ws, size_t ws_size,
                              hipStream_t stream) {
  (void)in_sizes; (void)n_in; (void)out_size; (void)ws_size;
  const float* x    = (const float*)d_in[0];
  const float* Wq   = (const float*)d_in[1];
  const float* Wk   = (const float*)d_in[2];
  const float* Wv   = (const float*)d_in[3];
  const float* Wo   = (const float*)d_in[4];
  const float* cosb = (const float*)d_in[5];
  const float* sinb = (const float*)d_in[6];

  const size_t MC = (size_t)M_ * C_;    // 6291456
  u16* ws = (u16*)d_ws;
  u16* Q   = ws;                        // [B][H][T][D] bf16 (pre-scaled)
  u16* K   = Q + MC;
  u16* Vt  = K + MC;                    // [B][H][D][T] bf16
  u16* Y   = Vt + MC;                   // [B*T][C] bf16
  float* out = (float*)d_out;

  qkv_fused<<<dim3(M_ / 128, H_), 256, 0, stream>>>(
      x, Wq, Wk, Wv, cosb, sinb, Q, K, Vt);

  attn_mfma<<<dim3(T_ / 128, B_ * H_), 256, 0, stream>>>(Q, K, Vt, Y);

  out_mfma<<<dim3(M_ / 128, H_), 256, 0, stream>>>(Y, Wo, out);
}

// Round 3
// 255.083 us; speedup vs baseline: 1.1146x; 1.0002x over previous
//
#include <hip/hip_runtime.h>
#include <hip/hip_bf16.h>
#include <stdint.h>

#define B_ 8
#define T_ 2048
#define C_ 384
#define H_ 6
#define D_ 64
#define M_ (B_*T_)   // 16384

typedef unsigned short u16;
typedef unsigned int u32;
typedef __attribute__((ext_vector_type(8))) short short8;
typedef __attribute__((ext_vector_type(4))) float floatx4;
typedef __attribute__((ext_vector_type(16))) float floatx16;

// softmax scale folded into stored Q: 0.125 * log2(e)
#define QSCALE 0.18033688011112042f

__device__ __forceinline__ u16 f2b(float f) {
  union { float f; unsigned u; } x; x.f = f;
  unsigned r = x.u + 0x7fffu + ((x.u >> 16) & 1u);  // round-nearest-even
  return (u16)(r >> 16);
}
__device__ __forceinline__ u32 pack_bf16(float a, float b) {
  union { __hip_bfloat162 h; u32 u; } x;
  x.h = __float22bfloat162_rn(float2{a, b});
  return x.u;
}
__device__ __forceinline__ uint4 pack8(const float4& lo, const float4& hi) {
  uint4 r;
  r.x = pack_bf16(lo.x, lo.y); r.y = pack_bf16(lo.z, lo.w);
  r.z = pack_bf16(hi.x, hi.y); r.w = pack_bf16(hi.z, hi.w);
  return r;
}

// v_permlane32_swap_b32: swaps a.hi(32 lanes) <-> b.lo(32 lanes).
__device__ __forceinline__ void plswap(u32& a, u32& b) {
  asm("v_permlane32_swap_b32 %0, %1" : "+v"(a), "+v"(b));
}

// ---------------------------------------------------------------------------
// Fused QKV projection.  XCD-locality remap: the 6 head-blocks of one
// m-block run on the same XCD so X rows are fetched once per XCD L2.
// ---------------------------------------------------------------------------
__global__ __launch_bounds__(256) void qkv_fused(
    const float* __restrict__ Xf,
    const float* __restrict__ Wqf, const float* __restrict__ Wkf, const float* __restrict__ Wvf,
    const float* __restrict__ cosb, const float* __restrict__ sinb,
    u16* __restrict__ Qo, u16* __restrict__ Ko, u16* __restrict__ Vto)
{
  __shared__ __align__(16) u16 smem[128 * 64 + 3 * 64 * 64];  // As | Bs[3] (40 KB)
  u16* As = smem;
  u16* Bs0 = smem + 128 * 64;

  // XCD remap: 768 wgs = 8 xcds x (16 m-blocks x 6 heads)
  const int id = blockIdx.x;
  const int xcd = id & 7;
  const int s = id >> 3;              // 0..95
  const int mb = xcd * 16 + s / 6;    // 0..127 (6 consecutive slots share mb)
  const int hh = s % 6;
  const int m0 = mb * 128;
  const int n0 = hh * 64;

  const int tid = threadIdx.x;
  const int w = tid >> 6;
  const int lane = tid & 63;
  const int quad = lane >> 4;
  const int c = lane & 15;

  const float* Wz[3] = {Wqf, Wkf, Wvf};

  floatx4 acc[3][2][4];
#pragma unroll
  for (int z = 0; z < 3; z++)
#pragma unroll
    for (int i = 0; i < 2; i++)
#pragma unroll
      for (int j = 0; j < 4; j++) acc[z][i][j] = (floatx4){0.f, 0.f, 0.f, 0.f};

  const int ra = tid >> 1, ca = (tid & 1) * 4;   // A: 2 thr/row, 4 chunks each
  const int rb = tid >> 2, cb = (tid & 3) * 2;   // B: 4 thr/row, 2 chunks each

  for (int k0 = 0; k0 < 384; k0 += 64) {
    float4 af[8];
#pragma unroll
    for (int j = 0; j < 4; j++) {
      const float* p = Xf + (size_t)(m0 + ra) * C_ + k0 + (ca + j) * 8;
      af[2 * j]     = *reinterpret_cast<const float4*>(p);
      af[2 * j + 1] = *reinterpret_cast<const float4*>(p + 4);
    }
    float4 bw[3][4];
#pragma unroll
    for (int z = 0; z < 3; z++)
#pragma unroll
      for (int u = 0; u < 2; u++) {
        const float* p = Wz[z] + (size_t)(n0 + rb) * C_ + k0 + (cb + u) * 8;
        bw[z][2 * u]     = *reinterpret_cast<const float4*>(p);
        bw[z][2 * u + 1] = *reinterpret_cast<const float4*>(p + 4);
      }
    __syncthreads();
#pragma unroll
    for (int j = 0; j < 4; j++)
      *reinterpret_cast<uint4*>(As + ra * 64 + (((ca + j) ^ (ra & 7)) * 8)) =
          pack8(af[2 * j], af[2 * j + 1]);
#pragma unroll
    for (int z = 0; z < 3; z++)
#pragma unroll
      for (int u = 0; u < 2; u++)
        *reinterpret_cast<uint4*>(Bs0 + z * 4096 + rb * 64 + (((cb + u) ^ (rb & 7)) * 8)) =
            pack8(bw[z][2 * u], bw[z][2 * u + 1]);
    __syncthreads();

#pragma unroll
    for (int ks = 0; ks < 2; ks++) {
      short8 af2[2];
#pragma unroll
      for (int mi = 0; mi < 2; mi++) {
        int row = w * 32 + mi * 16 + c;
        af2[mi] = *reinterpret_cast<const short8*>(
            As + row * 64 + (((ks * 4 + quad) ^ (row & 7)) * 8));
      }
#pragma unroll
      for (int z = 0; z < 3; z++) {
#pragma unroll
        for (int ni = 0; ni < 4; ni++) {
          int row = ni * 16 + c;
          short8 bf = *reinterpret_cast<const short8*>(
              Bs0 + z * 4096 + row * 64 + (((ks * 4 + quad) ^ (row & 7)) * 8));
#pragma unroll
          for (int mi = 0; mi < 2; mi++)
            acc[z][mi][ni] = __builtin_amdgcn_mfma_f32_16x16x32_bf16(af2[mi], bf, acc[z][mi][ni], 0, 0, 0);
        }
      }
    }
  }

  const int bb2 = m0 >> 11;
  const int tbase = m0 & (T_ - 1);

  // ---- V: register scatter to Vt[B][H][D][T] ----
  {
    const size_t vbase = ((size_t)(bb2 * H_ + hh)) * D_ * T_;
#pragma unroll
    for (int mi = 0; mi < 2; mi++) {
      int t = tbase + w * 32 + mi * 16 + quad * 4;
#pragma unroll
      for (int ni = 0; ni < 4; ni++) {
        int d = ni * 16 + c;
        ushort4 pk;
        pk.x = f2b(acc[2][mi][ni][0]); pk.y = f2b(acc[2][mi][ni][1]);
        pk.z = f2b(acc[2][mi][ni][2]); pk.w = f2b(acc[2][mi][ni][3]);
        *reinterpret_cast<ushort4*>(Vto + vbase + (size_t)d * T_ + t) = pk;
      }
    }
  }

  // ---- Q then K: lane-parallel RMS + RoPE, LDS transpose store ----
  u16* Ep = smem;
#pragma unroll
  for (int zz = 0; zz < 2; zz++) {
    __syncthreads();
#pragma unroll
    for (int mi = 0; mi < 2; mi++) {
      float ssr[4];
#pragma unroll
      for (int r = 0; r < 4; r++) {
        float s0 = acc[zz][mi][0][r], s1 = acc[zz][mi][1][r];
        float s2 = acc[zz][mi][2][r], s3 = acc[zz][mi][3][r];
        ssr[r] = s0 * s0 + s1 * s1 + s2 * s2 + s3 * s3;
      }
#pragma unroll
      for (int off = 1; off < 16; off <<= 1)
#pragma unroll
        for (int r = 0; r < 4; r++) ssr[r] += __shfl_xor(ssr[r], off, 64);
      int rowb = w * 32 + mi * 16 + quad * 4;
#pragma unroll
      for (int r = 0; r < 4; r++) {
        float scl = rsqrtf(ssr[r] * (1.0f / 64.0f) + 1e-5f);
        if (zz == 0) scl *= QSCALE;     // fold softmax scale into Q
        int t = tbase + rowb + r;
#pragma unroll
        for (int h2 = 0; h2 < 2; h2++) {
          float cs = cosb[t * 32 + h2 * 16 + c];
          float sn = sinb[t * 32 + h2 * 16 + c];
          float x1 = acc[zz][mi][h2][r];
          float x2 = acc[zz][mi][h2 + 2][r];
          Ep[(rowb + r) * 72 + h2 * 16 + c]       = f2b((x1 * cs + x2 * sn) * scl);
          Ep[(rowb + r) * 72 + (h2 + 2) * 16 + c] = f2b((x2 * cs - x1 * sn) * scl);
        }
      }
    }
    __syncthreads();
    {
      int row = tid >> 1, half = tid & 1;
      int t = tbase + row;
      u16* Og = (zz == 0) ? Qo : Ko;
      u16* dst = Og + (((size_t)(bb2 * H_ + hh)) * T_ + t) * D_ + half * 32;
#pragma unroll
      for (int i = 0; i < 4; i++)
        *reinterpret_cast<uint4*>(dst + i * 8) =
            *reinterpret_cast<const uint4*>(Ep + row * 72 + half * 32 + i * 8);
    }
  }
}

// ---------------------------------------------------------------------------
// MFMA flash attention — 32x32x16 swapped-QK^T, in-register softmax.
// Round-3: R3 bit-rotated LDS swizzle (kills 4-way staging-write conflicts:
// row stride is 128 B == 0 mod banks, so only the XOR slot picks the bank;
// R3 varies bit2 across 4-row groups), double-buffered K/V with ONE barrier
// per tile, XCD-locality remap (16 q-blocks of a bh share an XCD -> K/V
// L2-resident), s_setprio around MFMA clusters.
// ---------------------------------------------------------------------------
__global__ __launch_bounds__(256, 3) void attn_mfma(
    const u16* __restrict__ Qg, const u16* __restrict__ Kg,
    const u16* __restrict__ Vtg, u16* __restrict__ Yg)
{
  // two buffers: buf b at smem + b*8192: Ks[4096] | Vs[4096] u16 (32 KB total)
  __shared__ __align__(16) u16 smem[16384];

  const int tid = threadIdx.x;
  const int w = tid >> 6;
  const int lane = tid & 63;
  const int hi = lane >> 5;
  const int lq = lane & 31;

  // XCD remap: 768 wgs = 8 xcds x (6 bh x 16 q-blocks)
  const int id = blockIdx.x;
  const int xcd = id & 7;
  const int slot = id >> 3;              // 0..95
  const int bh = xcd * 6 + (slot >> 4);  // 0..47
  const int q0 = (slot & 15) * 128;

  const size_t baseQK = (size_t)bh * T_ * D_;
  const size_t baseV  = (size_t)bh * D_ * T_;

  // Q fragments (B-operand): lane holds Q[q0+w*32+lq][ds*16 + hi*8 + j]
  short8 qf[4];
  {
    const u16* qp = Qg + baseQK + (size_t)(q0 + w * 32 + lq) * D_ + hi * 8;
#pragma unroll
    for (int d = 0; d < 4; d++)
      qf[d] = *reinterpret_cast<const short8*>(qp + d * 16);
  }

  floatx16 z16;
#pragma unroll
  for (int i = 0; i < 16; i++) z16[i] = 0.f;
  short8 vones;
#pragma unroll
  for (int i = 0; i < 8; i++) vones[i] = (short)0x3F80;

  // staging: 256 threads cover 64 rows x 2 x 16B chunks; R3 slot swizzle
  const int sr = tid >> 2;
  const int sch = tid & 3;
  const int r3s = ((sr & 3) << 1) | ((sr >> 2) & 1);   // R3(sr&7)
  const int ko0 = sr * 64 + ((sch ^ r3s) * 8);
  const int ko1 = sr * 64 + (((sch + 4) ^ r3s) * 8);
  const int vo0 = 4096 + ko0;
  const int vo1 = 4096 + ko1;
  const u16* kga = Kg + baseQK + (size_t)sr * D_ + sch * 8;
  const u16* vga = Vtg + baseV + (size_t)sr * T_ + sch * 8;

  // prologue: tile 0 -> regs -> buf0; then prefetch tile 1 into regs
  uint4 ka = *reinterpret_cast<const uint4*>(kga);
  uint4 kb = *reinterpret_cast<const uint4*>(kga + 32);
  uint4 va = *reinterpret_cast<const uint4*>(vga);
  uint4 vb = *reinterpret_cast<const uint4*>(vga + 32);
  *reinterpret_cast<uint4*>(smem + ko0) = ka;
  *reinterpret_cast<uint4*>(smem + ko1) = kb;
  *reinterpret_cast<uint4*>(smem + vo0) = va;
  *reinterpret_cast<uint4*>(smem + vo1) = vb;
  const u16* kload = kga + (size_t)64 * D_;
  const u16* vload = vga + 64;
  ka = *reinterpret_cast<const uint4*>(kload);
  kb = *reinterpret_cast<const uint4*>(kload + 32);
  va = *reinterpret_cast<const uint4*>(vload);
  vb = *reinterpret_cast<const uint4*>(vload + 32);
  kload += (size_t)64 * D_;
  vload += 64;

  floatx16 o0 = z16, o1 = z16;
  floatx16 l_acc = z16;

  const int r3q = ((lq & 3) << 1) | ((lq >> 2) & 1);   // R3(lq&7)

  for (int kt = 0; kt < 32; kt++) {
    __syncthreads();   // buf[kt&1] fully written; buf[(kt+1)&1] fully read

    // write prefetched tile kt+1 into the other buffer; issue loads kt+2
    if (kt < 31) {
      u16* wb = smem + (((kt + 1) & 1) << 13);
      *reinterpret_cast<uint4*>(wb + ko0) = ka;
      *reinterpret_cast<uint4*>(wb + ko1) = kb;
      *reinterpret_cast<uint4*>(wb + vo0) = va;
      *reinterpret_cast<uint4*>(wb + vo1) = vb;
      if (kt < 30) {
        ka = *reinterpret_cast<const uint4*>(kload);
        kb = *reinterpret_cast<const uint4*>(kload + 32);
        va = *reinterpret_cast<const uint4*>(vload);
        vb = *reinterpret_cast<const uint4*>(vload + 32);
        kload += (size_t)64 * D_;
        vload += 64;
      }
    }

    const u16* Ksb = smem + ((kt & 1) << 13);
    const u16* Vsb = Ksb + 4096;

    // ---- QK^T (swapped): st = K * Q^T, col = q (lane-local), rows = t ----
    floatx16 st0, st1;
    __builtin_amdgcn_s_setprio(1);
    {
      const int xr = hi ^ r3q;
      short8 kf0 = *reinterpret_cast<const short8*>(Ksb + lq * 64 + xr * 8);
      short8 kf1 = *reinterpret_cast<const short8*>(Ksb + (32 + lq) * 64 + xr * 8);
      st0 = __builtin_amdgcn_mfma_f32_32x32x16_bf16(kf0, qf[0], z16, 0, 0, 0);
      st1 = __builtin_amdgcn_mfma_f32_32x32x16_bf16(kf1, qf[0], z16, 0, 0, 0);
    }
#pragma unroll
    for (int ds = 1; ds < 4; ds++) {
      const int xr = (ds * 2 + hi) ^ r3q;
      short8 kf0 = *reinterpret_cast<const short8*>(Ksb + lq * 64 + xr * 8);
      short8 kf1 = *reinterpret_cast<const short8*>(Ksb + (32 + lq) * 64 + xr * 8);
      st0 = __builtin_amdgcn_mfma_f32_32x32x16_bf16(kf0, qf[ds], st0, 0, 0, 0);
      st1 = __builtin_amdgcn_mfma_f32_32x32x16_bf16(kf1, qf[ds], st1, 0, 0, 0);
    }
    __builtin_amdgcn_s_setprio(0);

    // ---- softmax: p = exp2(s)  (scale folded into Q, bias cancels) ----
#pragma unroll
    for (int r = 0; r < 16; r++) {
      st0[r] = exp2f(st0[r]);
      st1[r] = exp2f(st1[r]);
    }

    // ---- P -> bf16 A-fragments: 16 cvt_pk + 8 permlane32_swap ----
    short8 pa[4];
#pragma unroll
    for (int ks = 0; ks < 4; ks++) {
      const floatx16& s = (ks < 2) ? st0 : st1;
      const int rb = (ks & 1) * 8;
      u32 ca = pack_bf16(s[rb + 0], s[rb + 1]);
      u32 cb = pack_bf16(s[rb + 2], s[rb + 3]);
      u32 cc = pack_bf16(s[rb + 4], s[rb + 5]);
      u32 cd = pack_bf16(s[rb + 6], s[rb + 7]);
      plswap(ca, cc);
      plswap(cb, cd);
      short8 pf;
      u32* pfu = reinterpret_cast<u32*>(&pf);
      pfu[0] = ca; pfu[1] = cb; pfu[2] = cc; pfu[3] = cd;
      pa[ks] = pf;
    }

    // ---- PV + l row-sums ----
    __builtin_amdgcn_s_setprio(1);
#pragma unroll
    for (int nt = 0; nt < 2; nt++) {
      const int d = nt * 32 + lq;
      floatx16& o = nt ? o1 : o0;
#pragma unroll
      for (int ks = 0; ks < 4; ks++) {
        short8 vf = *reinterpret_cast<const short8*>(
            Vsb + d * 64 + (((ks * 2 + hi) ^ r3q) * 8));
        o = __builtin_amdgcn_mfma_f32_32x32x16_bf16(pa[ks], vf, o, 0, 0, 0);
      }
    }
#pragma unroll
    for (int ks = 0; ks < 4; ks++)
      l_acc = __builtin_amdgcn_mfma_f32_32x32x16_bf16(pa[ks], vones, l_acc, 0, 0, 0);
    __builtin_amdgcn_s_setprio(0);
  }

  // normalization: l_acc[r] holds l for exactly the q-row o[r] holds
  float invr[16];
#pragma unroll
  for (int r = 0; r < 16; r++) invr[r] = __builtin_amdgcn_rcpf(l_acc[r]);

  __syncthreads();   // done with K/V buffers; reuse smem for epilogue
  u16* Ep = smem + w * (32 * 72);
#pragma unroll
  for (int nt = 0; nt < 2; nt++) {
    const floatx16& o = nt ? o1 : o0;
#pragma unroll
    for (int r = 0; r < 16; r++) {
      const int rl = (r & 3) + 8 * (r >> 2) + 4 * hi;
      Ep[rl * 72 + nt * 32 + lq] = f2b(o[r] * invr[r]);
    }
  }
  __syncthreads();
  {
    const int row = tid >> 1, half = tid & 1;   // 128 rows x 2 halves of 64B
    const u16* src = smem + (row >> 5) * (32 * 72) + (row & 31) * 72 + half * 32;
    const int t = q0 + row;
    const int b = bh / H_, h = bh % H_;
    const size_t yi = ((size_t)b * T_ + t) * C_ + (size_t)h * 64 + half * 32;
#pragma unroll
    for (int i = 0; i < 4; i++)
      *reinterpret_cast<uint4*>(Yg + yi + i * 8) =
          *reinterpret_cast<const uint4*>(src + i * 8);
  }
}

// ---------------------------------------------------------------------------
// Out projection.  XCD-locality remap: the 6 col-blocks of one m-block share
// an XCD so Y rows are fetched once per XCD L2.
// ---------------------------------------------------------------------------
__global__ __launch_bounds__(256) void out_mfma(
    const u16* __restrict__ Xb, const float* __restrict__ Wf, float* __restrict__ Og)
{
  __shared__ __align__(16) u16 smem[17408];   // As|Bs, then fp32 Ep (34816 B)
  u16* As = smem;
  u16* Bs = smem + 128 * 64;

  const int id = blockIdx.x;
  const int xcd = id & 7;
  const int s = id >> 3;              // 0..95
  const int m0 = (xcd * 16 + s / 6) * 128;
  const int n0 = (s % 6) * 64;

  const int tid = threadIdx.x;
  const int w = tid >> 6;
  const int lane = tid & 63;
  const int quad = lane >> 4;
  const int c = lane & 15;

  floatx4 acc[2][4];
#pragma unroll
  for (int i = 0; i < 2; i++)
#pragma unroll
    for (int j = 0; j < 4; j++) acc[i][j] = (floatx4){0.f, 0.f, 0.f, 0.f};

  const int ra = tid >> 1, ca = (tid & 1) * 4;
  const int rb = tid >> 2, cb = (tid & 3) * 2;

  for (int k0 = 0; k0 < 384; k0 += 64) {
    uint4 a[4];
#pragma unroll
    for (int j = 0; j < 4; j++)
      a[j] = *reinterpret_cast<const uint4*>(Xb + (size_t)(m0 + ra) * C_ + k0 + (ca + j) * 8);
    float4 bw[4];
#pragma unroll
    for (int u = 0; u < 2; u++) {
      const float* p = Wf + (size_t)(n0 + rb) * C_ + k0 + (cb + u) * 8;
      bw[2 * u]     = *reinterpret_cast<const float4*>(p);
      bw[2 * u + 1] = *reinterpret_cast<const float4*>(p + 4);
    }
    __syncthreads();
#pragma unroll
    for (int j = 0; j < 4; j++)
      *reinterpret_cast<uint4*>(As + ra * 64 + (((ca + j) ^ (ra & 7)) * 8)) = a[j];
#pragma unroll
    for (int u = 0; u < 2; u++)
      *reinterpret_cast<uint4*>(Bs + rb * 64 + (((cb + u) ^ (rb & 7)) * 8)) =
          pack8(bw[2 * u], bw[2 * u + 1]);
    __syncthreads();

#pragma unroll
    for (int ks = 0; ks < 2; ks++) {
      short8 af[2], bf[4];
#pragma unroll
      for (int mi = 0; mi < 2; mi++) {
        int row = w * 32 + mi * 16 + c;
        af[mi] = *reinterpret_cast<const short8*>(
            As + row * 64 + (((ks * 4 + quad) ^ (row & 7)) * 8));
      }
#pragma unroll
      for (int ni = 0; ni < 4; ni++) {
        int row = ni * 16 + c;
        bf[ni] = *reinterpret_cast<const short8*>(
            Bs + row * 64 + (((ks * 4 + quad) ^ (row & 7)) * 8));
      }
#pragma unroll
      for (int mi = 0; mi < 2; mi++)
#pragma unroll
        for (int ni = 0; ni < 4; ni++)
          acc[mi][ni] = __builtin_amdgcn_mfma_f32_16x16x32_bf16(af[mi], bf[ni], acc[mi][ni], 0, 0, 0);
    }
  }

  __syncthreads();
  float* Ep = reinterpret_cast<float*>(smem) + w * (32 * 68);
#pragma unroll
  for (int mi = 0; mi < 2; mi++)
#pragma unroll
    for (int ni = 0; ni < 4; ni++) {
      int rw = mi * 16 + quad * 4;
      int col = ni * 16 + c;
#pragma unroll
      for (int r = 0; r < 4; r++)
        Ep[(rw + r) * 68 + col] = acc[mi][ni][r];
    }
  __syncthreads();
  {
    int rw2 = lane >> 1, half = lane & 1;
    const float* src = Ep + rw2 * 68 + half * 32;
    float* dst = Og + (size_t)(m0 + w * 32 + rw2) * C_ + n0 + half * 32;
#pragma unroll
    for (int i = 0; i < 8; i++)
      *reinterpret_cast<float4*>(dst + i * 4) =
          *reinterpret_cast<const float4*>(src + i * 4);
  }
}

// ---------------------------------------------------------------------------
extern "C" void kernel_launch(void* const* d_in, const int* in_sizes, int n_in,
                              void* d_out, int out_size, void* d_ws, size_t ws_size,
                              hipStream_t stream) {
  (void)in_sizes; (void)n_in; (void)out_size; (void)ws_size;
  const float* x    = (const float*)d_in[0];
  const float* Wq   = (const float*)d_in[1];
  const float* Wk   = (const float*)d_in[2];
  const float* Wv   = (const float*)d_in[3];
  const float* Wo   = (const float*)d_in[4];
  const float* cosb = (const float*)d_in[5];
  const float* sinb = (const float*)d_in[6];

  const size_t MC = (size_t)M_ * C_;    // 6291456
  u16* ws = (u16*)d_ws;
  u16* Q   = ws;                        // [B][H][T][D] bf16 (pre-scaled)
  u16* K   = Q + MC;
  u16* Vt  = K + MC;                    // [B][H][D][T] bf16
  u16* Y   = Vt + MC;                   // [B*T][C] bf16
  float* out = (float*)d_out;

  qkv_fused<<<768, 256, 0, stream>>>(x, Wq, Wk, Wv, cosb, sinb, Q, K, Vt);

  attn_mfma<<<768, 256, 0, stream>>>(Q, K, Vt, Y);

  out_mfma<<<768, 256, 0, stream>>>(Y, Wo, out);
}